// Round 10
// baseline (614.345 us; speedup 1.0000x reference)
//
#include <hip/hip_runtime.h>

// SPModel_6846177870356: y = x@W^T + all2all permute. M=28160, N=K=2048.
// Inputs FP32 (harness-upcast fp16), output FP32.
// Round 10: 256x256 4-phase pipelined GEMM (T3+T4+T5 on top of R9's T2):
//  - pre-convert X,W -> f16 pre-swizzled in d_ws (R9-verified converts)
//  - 8 waves (2Mx4N), per-wave 128x64, acc 8x4 f32x4
//  - raw s_barrier + counted vmcnt(2) (never 0 in loop): tile t+1's 8
//    global_load_lds stay in flight across tile t's 4 phases of compute
//  - per phase: stage 2 loads; [p0: vmcnt(2)]; barrier; ds_read quadrant
//    frags (swizzled, conflict-free); barrier; setprio(1) 16 MFMA setprio(0);
//    barrier.  B-frags cached across qm pairs (24 vs 32 b128/lane/tile).

typedef _Float16 f16;
typedef _Float16 f16x2 __attribute__((ext_vector_type(2)));
typedef _Float16 f16x8 __attribute__((ext_vector_type(8)));
typedef float    f32x4 __attribute__((ext_vector_type(4)));

#define GPTR(p) ((const __attribute__((address_space(1))) void*)(p))
#define LPTR(p) ((__attribute__((address_space(3))) void*)(p))

constexpr int Mdim = 28160;   // 8*44*80
constexpr int Ndim = 2048;
constexpr int Kdim = 2048;
constexpr int BM = 256, BN = 256, BK = 64;
constexpr int NTHREADS = 512;
constexpr int NWG = (Mdim / BM) * (Ndim / BN);  // 110*8 = 880 (%8==0)
constexpr int NT  = Kdim / BK;                  // 32
constexpr size_t XS_ELEMS = (size_t)Mdim * Kdim;
constexpr size_t WS_ELEMS = (size_t)Ndim * Kdim;
constexpr size_t WS_NEED  = (XS_ELEMS + WS_ELEMS) * sizeof(f16);

__device__ __forceinline__ f16x8 pack8(const f32x4& lo, const f32x4& hi) {
    f16x2 p0 = __builtin_bit_cast(f16x2, __builtin_amdgcn_cvt_pkrtz(lo[0], lo[1]));
    f16x2 p1 = __builtin_bit_cast(f16x2, __builtin_amdgcn_cvt_pkrtz(lo[2], lo[3]));
    f16x2 p2 = __builtin_bit_cast(f16x2, __builtin_amdgcn_cvt_pkrtz(hi[0], hi[1]));
    f16x2 p3 = __builtin_bit_cast(f16x2, __builtin_amdgcn_cvt_pkrtz(hi[2], hi[3]));
    return (f16x8){p0[0], p0[1], p1[0], p1[1], p2[0], p2[1], p3[0], p3[1]};
}

// f32 [rows x 2048] -> f16 pre-swizzled: dst[m][(k8 ^ (m&7))*8] (16B chunks).
__global__ __launch_bounds__(256)
void convert_kernel(const float* __restrict__ src, f16* __restrict__ dst) {
    const int idx = blockIdx.x * 256 + threadIdx.x;
    const int m   = idx >> 8;
    const int k8  = idx & 255;
    const int k8s = k8 ^ (m & 7);
    const float* p = src + (size_t)m * Kdim + k8 * 8;
    f32x4 lo = *(const f32x4*)p;
    f32x4 hi = *(const f32x4*)(p + 4);
    *(f16x8*)(dst + (size_t)m * Kdim + k8s * 8) = pack8(lo, hi);
}

__global__ __launch_bounds__(512, 2)
void gemm_a2a_kernel(const f16* __restrict__ Xs, const f16* __restrict__ Ws,
                     float* __restrict__ out) {
    __shared__ f16 sA[2][BM * BK];   // 32 KiB per buf (swizzled image)
    __shared__ f16 sB[2][BN * BK];   // total 128 KiB

    const int tid  = threadIdx.x;
    const int lane = tid & 63;
    const int wid  = tid >> 6;
    const int wm   = wid >> 2;          // 0..1
    const int wn   = wid & 3;           // 0..3

    const int cpx  = NWG >> 3;                       // XCD-bijective swizzle
    const int tile = (blockIdx.x & 7) * cpx + (blockIdx.x >> 3);
    const int bn   = tile & 7;
    const int bm   = tile >> 3;
    const int row0 = bm * BM;
    const int col0 = bn * BN;

    f32x4 acc[8][4] = {};   // 8 M-frags x 4 N-frags

    // stage chunk-pair i (A,B) of tile t into buf d (2 x global_load_lds, 16B)
    auto stage1 = [&](int t, int i, int d) {
        const int c8 = i * NTHREADS + tid;   // 2048 chunks per 256x64 tile
        const int r  = c8 >> 3;
        const int cc = (c8 & 7) * 8;
        __builtin_amdgcn_global_load_lds(
            GPTR(Xs + (size_t)(row0 + r) * Kdim + t * BK + cc),
            LPTR(&sA[d][c8 * 8]), 16, 0, 0);
        __builtin_amdgcn_global_load_lds(
            GPTR(Ws + (size_t)(col0 + r) * Kdim + t * BK + cc),
            LPTR(&sB[d][c8 * 8]), 16, 0, 0);
    };

    // prologue: all 4 chunk-pairs of tile 0 -> buf 0 (8 loads in flight)
#pragma unroll
    for (int i = 0; i < 4; ++i) stage1(0, i, 0);

    for (int t = 0; t < NT; ++t) {
        const int d  = t & 1;
        const int tn = (t + 1 < NT) ? t + 1 : t;   // tail re-stage: harmless
        const f16* Ab = sA[d];
        const f16* Bb = sB[d];
        f16x8 bq[2][2];   // cached B frags for current qn (reused across qm)
#pragma unroll
        for (int p = 0; p < 4; ++p) {
            const int qm = p & 1, qn = p >> 1;   // quadrant order 00,10,01,11
            stage1(tn, p, d ^ 1);                 // buf d^1: last read ended t-1
            if (p == 0) {
                // tile t's 8 loads must land; 2 newest (just issued) may fly.
                asm volatile("s_waitcnt vmcnt(2)" ::: "memory");
            }
            __builtin_amdgcn_s_barrier();         // all waves' t-loads landed
            if (p == 0) __builtin_amdgcn_sched_barrier(0);

            if ((p & 1) == 0) {                   // p==0/2: load B frags for qn
#pragma unroll
                for (int g = 0; g < 2; ++g)
#pragma unroll
                    for (int ks = 0; ks < 2; ++ks) {
                        const int rB = wn * 64 + qn * 32 + g * 16 + (lane & 15);
                        const int kc = ks * 32 + (lane >> 4) * 8;
                        const int bb = ((rB * BK + kc) * 2) ^ ((rB & 7) << 4);
                        bq[g][ks] = *(const f16x8*)((const char*)Bb + bb);
                    }
            }
            f16x8 aq[4][2];
#pragma unroll
            for (int f = 0; f < 4; ++f)
#pragma unroll
                for (int ks = 0; ks < 2; ++ks) {
                    const int rA = wm * 128 + qm * 64 + f * 16 + (lane & 15);
                    const int kc = ks * 32 + (lane >> 4) * 8;
                    const int ba = ((rA * BK + kc) * 2) ^ ((rA & 7) << 4);
                    aq[f][ks] = *(const f16x8*)((const char*)Ab + ba);
                }
            __builtin_amdgcn_s_barrier();         // lockstep before MFMA burst

            __builtin_amdgcn_s_setprio(1);
#pragma unroll
            for (int f = 0; f < 4; ++f)
#pragma unroll
                for (int g = 0; g < 2; ++g)
#pragma unroll
                    for (int ks = 0; ks < 2; ++ks)
                        acc[qm * 4 + f][qn * 2 + g] =
                            __builtin_amdgcn_mfma_f32_16x16x32_f16(
                                aq[f][ks], bq[g][ks],
                                acc[qm * 4 + f][qn * 2 + g], 0, 0, 0);
            __builtin_amdgcn_s_setprio(0);
            __builtin_amdgcn_s_barrier();         // tile-boundary safety barrier
        }
    }

    // Epilogue: C/D col=lane&15 (n), row=(lane>>4)*4+j (m); fused all2all.
    const int R0 = row0 + wm * 128;
    const int C0 = col0 + wn * 64;
#pragma unroll
    for (int mi = 0; mi < 8; ++mi)
#pragma unroll
        for (int ni = 0; ni < 4; ++ni) {
            const int n     = C0 + ni * 16 + (lane & 15);
            const int rbase = R0 + mi * 16 + (lane >> 4) * 4;
            const size_t obase = (size_t)(n >> 8) * ((size_t)Mdim * 256) + (n & 255);
#pragma unroll
            for (int j = 0; j < 4; ++j)
                out[obase + (size_t)(rbase + j) * 256] = acc[mi][ni][j];
        }
}

// ---- Fallback (R7-verified): direct-f32 reg-staged dbuf 128^2 kernel ----
constexpr int FBM = 128, FBK = 64;
constexpr int FNWG = (Mdim / FBM) * (Ndim / FBM);
__global__ __launch_bounds__(256)
void gemm_a2a_f32_kernel(const float* __restrict__ X, const float* __restrict__ W,
                         float* __restrict__ out) {
    __shared__ f16 sA[2][FBM * FBK];
    __shared__ f16 sB[2][FBM * FBK];
    const int tid  = threadIdx.x;
    const int lane = tid & 63;
    const int wid  = tid >> 6;
    const int wr   = wid >> 1;
    const int wc   = wid & 1;
    const int cpx  = FNWG >> 3;
    const int tile = (blockIdx.x & 7) * cpx + (blockIdx.x >> 3);
    const int bn   = tile & 15;
    const int bm   = tile >> 4;
    const int row0 = bm * FBM;
    const int col0 = bn * FBM;
    f32x4 acc[4][4] = {};
    f32x4 ra[8], rb[8];
    auto load_tile = [&](int t) {
#pragma unroll
        for (int i = 0; i < 4; ++i) {
            const int c8 = i * 256 + tid;
            const int r  = c8 >> 3;
            const int cc = (c8 & 7) * 8;
            const float* pa = X + (size_t)(row0 + r) * Kdim + t * FBK + cc;
            const float* pb = W + (size_t)(col0 + r) * Kdim + t * FBK + cc;
            ra[2*i] = *(const f32x4*)pa; ra[2*i+1] = *(const f32x4*)(pa + 4);
            rb[2*i] = *(const f32x4*)pb; rb[2*i+1] = *(const f32x4*)(pb + 4);
        }
    };
    int cur = 0;
    load_tile(0);
    for (int t = 0; t < Kdim / FBK; ++t) {
#pragma unroll
        for (int i = 0; i < 4; ++i) {
            const int c8 = i * 256 + tid;
            const int sb = (c8 * 16) ^ (((c8 >> 3) & 7) << 4);
            *(f16x8*)((char*)sA[cur] + sb) = pack8(ra[2*i], ra[2*i+1]);
            *(f16x8*)((char*)sB[cur] + sb) = pack8(rb[2*i], rb[2*i+1]);
        }
        if (t + 1 < Kdim / FBK) load_tile(t + 1);
        __syncthreads();
        const f16* Ab = sA[cur];
        const f16* Bb = sB[cur];
#pragma unroll
        for (int kk = 0; kk < FBK; kk += 32) {
            const int kc = kk + (lane >> 4) * 8;
            f16x8 af[4], bfr[4];
#pragma unroll
            for (int f = 0; f < 4; ++f) {
                const int rowA = wr * 64 + f * 16 + (lane & 15);
                af[f] = *(const f16x8*)((const char*)Ab + (((rowA * FBK + kc) * 2) ^ ((rowA & 7) << 4)));
                const int rowB = wc * 64 + f * 16 + (lane & 15);
                bfr[f] = *(const f16x8*)((const char*)Bb + (((rowB * FBK + kc) * 2) ^ ((rowB & 7) << 4)));
            }
#pragma unroll
            for (int mi = 0; mi < 4; ++mi)
#pragma unroll
                for (int ni = 0; ni < 4; ++ni)
                    acc[mi][ni] = __builtin_amdgcn_mfma_f32_16x16x32_f16(
                        af[mi], bfr[ni], acc[mi][ni], 0, 0, 0);
        }
        cur ^= 1;
    }
#pragma unroll
    for (int mi = 0; mi < 4; ++mi)
#pragma unroll
        for (int ni = 0; ni < 4; ++ni) {
            const int n     = col0 + wc * 64 + ni * 16 + (lane & 15);
            const int rbase = row0 + wr * 64 + mi * 16 + (lane >> 4) * 4;
            const size_t obase = (size_t)(n >> 8) * ((size_t)Mdim * 256) + (n & 255);
#pragma unroll
            for (int j = 0; j < 4; ++j)
                out[obase + (size_t)(rbase + j) * 256] = acc[mi][ni][j];
        }
}

extern "C" void kernel_launch(void* const* d_in, const int* in_sizes, int n_in,
                              void* d_out, int out_size, void* d_ws, size_t ws_size,
                              hipStream_t stream) {
    const float* X = (const float*)d_in[0];
    const float* W = (const float*)d_in[1];
    float* out     = (float*)d_out;
    if (ws_size >= WS_NEED) {
        f16* Xs = (f16*)d_ws;
        f16* Ws = Xs + XS_ELEMS;
        hipLaunchKernelGGL(convert_kernel, dim3((int)(XS_ELEMS / 8 / 256)), dim3(256),
                           0, stream, X, Xs);
        hipLaunchKernelGGL(convert_kernel, dim3((int)(WS_ELEMS / 8 / 256)), dim3(256),
                           0, stream, W, Ws);
        hipLaunchKernelGGL(gemm_a2a_kernel, dim3(NWG), dim3(512), 0, stream, Xs, Ws, out);
    } else {
        hipLaunchKernelGGL(gemm_a2a_f32_kernel, dim3(FNWG), dim3(256), 0, stream, X, W, out);
    }
}

// Round 11
// 436.100 us; speedup vs baseline: 1.4087x; 1.4087x over previous
//
#include <hip/hip_runtime.h>

// SPModel_6846177870356: y = x@W^T + all2all permute. M=28160, N=K=2048.
// Inputs FP32 (harness-upcast fp16), output FP32.
// Round 11: 256x256 tile, BK=32, TRIPLE-buffered LDS (96KB), stagger-2
// staging with ONE vmcnt(4) + ONE raw s_barrier per K-tile (T3/T4 by
// construction; count-verified). Row-pair 128B-line XOR-swizzled LDS layout
// (conflict-free b128 reads) staged via pre-swizzled per-lane global source +
// linear LDS dest (G21/m173). 8 waves (2Mx4N), per-wave 128x64, 32 MFMA/iter
// with setprio(1) (T5). XCD-bijective swizzle. Fused all2all f32 epilogue.

typedef _Float16 f16;
typedef _Float16 f16x2 __attribute__((ext_vector_type(2)));
typedef _Float16 f16x8 __attribute__((ext_vector_type(8)));
typedef float    f32x4 __attribute__((ext_vector_type(4)));

#define GPTR(p) ((const __attribute__((address_space(1))) void*)(p))
#define LPTR(p) ((__attribute__((address_space(3))) void*)(p))

constexpr int Mdim = 28160;   // 8*44*80
constexpr int Ndim = 2048;
constexpr int Kdim = 2048;
constexpr int BM = 256, BN = 256, BK = 32;
constexpr int NWG = (Mdim / BM) * (Ndim / BN);  // 110*8 = 880 (%8==0)
constexpr int NT  = Kdim / BK;                  // 64
constexpr size_t XS_ELEMS = (size_t)Mdim * Kdim;
constexpr size_t WS_ELEMS = (size_t)Ndim * Kdim;
constexpr size_t WS_NEED  = (XS_ELEMS + WS_ELEMS) * sizeof(f16);

__device__ __forceinline__ f16x8 pack8(const f32x4& lo, const f32x4& hi) {
    f16x2 p0 = __builtin_bit_cast(f16x2, __builtin_amdgcn_cvt_pkrtz(lo[0], lo[1]));
    f16x2 p1 = __builtin_bit_cast(f16x2, __builtin_amdgcn_cvt_pkrtz(lo[2], lo[3]));
    f16x2 p2 = __builtin_bit_cast(f16x2, __builtin_amdgcn_cvt_pkrtz(hi[0], hi[1]));
    f16x2 p3 = __builtin_bit_cast(f16x2, __builtin_amdgcn_cvt_pkrtz(hi[2], hi[3]));
    return (f16x8){p0[0], p0[1], p1[0], p1[1], p2[0], p2[1], p3[0], p3[1]};
}

// plain linear f32 -> f16 convert (16B-chunk vectorized)
__global__ __launch_bounds__(256)
void convert_kernel(const float* __restrict__ src, f16* __restrict__ dst) {
    const size_t idx = ((size_t)blockIdx.x * 256 + threadIdx.x) * 8;
    f32x4 lo = *(const f32x4*)(src + idx);
    f32x4 hi = *(const f32x4*)(src + idx + 4);
    *(f16x8*)(dst + idx) = pack8(lo, hi);
}

// LDS tile layout (per 256x32 tile, 16KB): line L=r>>1 is 128B holding rows
// {2L,2L+1}; byte_in_line = ((r&1)*64 + kc*2) ^ ((L&7)<<4).
__device__ __forceinline__ f16x8 lds_frag(const f16* base, int r, int kc) {
    const int line = r >> 1;
    const int b    = (((r & 1) << 6) + (kc << 1)) ^ ((line & 7) << 4);
    return *(const f16x8*)((const char*)base + line * 128 + b);
}

__global__ __launch_bounds__(512, 2)
void gemm_a2a_kernel(const f16* __restrict__ Xs, const f16* __restrict__ Ws,
                     float* __restrict__ out) {
    __shared__ f16 sA[3][BM * BK];   // 3 x 16 KiB
    __shared__ f16 sB[3][BN * BK];   // 3 x 16 KiB  (total 96 KiB)

    const int tid  = threadIdx.x;
    const int lane = tid & 63;
    const int wid  = tid >> 6;
    const int wm   = wid >> 2;          // 0..1 -> 128 M-rows
    const int wn   = wid & 3;           // 0..3 -> 64 N-rows

    const int cpx  = NWG >> 3;                       // XCD-bijective swizzle
    const int tile = (blockIdx.x & 7) * cpx + (blockIdx.x >> 3);
    const int bn   = tile & 7;
    const int bm   = tile >> 3;
    const int row0 = bm * BM;
    const int col0 = bn * BN;

    f32x4 acc[8][4] = {};

    // Stage one K-tile (A+B, 4 gload_lds/thread). Linear LDS dest chunk c;
    // global source pre-swizzled per-lane so the linear image IS the swizzled
    // layout: u = (c&7) ^ ((c>>3)&7); r = 2*(c>>3) + (u>>2); k8 = u&3.
    auto stage = [&](int t, f16* dA, f16* dB) {
#pragma unroll
        for (int h = 0; h < 2; ++h) {
            const int c    = h * 512 + tid;           // 1024 chunks per tile
            const int line = c >> 3;
            const int u    = (c & 7) ^ (line & 7);
            const int r    = 2 * line + (u >> 2);
            const int koff = (u & 3) * 8;
            __builtin_amdgcn_global_load_lds(
                GPTR(Xs + (size_t)(row0 + r) * Kdim + t * BK + koff),
                LPTR(dA + c * 8), 16, 0, 0);
            __builtin_amdgcn_global_load_lds(
                GPTR(Ws + (size_t)(col0 + r) * Kdim + t * BK + koff),
                LPTR(dB + c * 8), 16, 0, 0);
        }
    };

    f16 *A0 = sA[0], *A1 = sA[1], *A2 = sA[2];
    f16 *B0 = sB[0], *B1 = sB[1], *B2 = sB[2];
    stage(0, A0, B0);            // 4 loads in flight
    stage(1, A1, B1);            // 8 in flight

    for (int t = 0; t < NT; ++t) {
        // outstanding here: tile t (oldest 4) + t+1 (+ t+2 issued below later).
        if (t < NT - 1) asm volatile("s_waitcnt vmcnt(4)" ::: "memory");
        else            asm volatile("s_waitcnt vmcnt(0)" ::: "memory");
        __builtin_amdgcn_s_barrier();   // tile t fully in LDS for ALL waves;
                                        // all waves done reading tile t-1.
        if (t + 2 < NT) stage(t + 2, A2, B2);   // buf of t-1: safe to overwrite

        const int kc = (lane >> 4) * 8;          // frag k = kc..kc+7 (BK=32)
        f16x8 a[8], b[4];
#pragma unroll
        for (int f = 0; f < 8; ++f)
            a[f] = lds_frag(A0, wm * 128 + f * 16 + (lane & 15), kc);
#pragma unroll
        for (int g = 0; g < 4; ++g)
            b[g] = lds_frag(B0, wn * 64 + g * 16 + (lane & 15), kc);

        __builtin_amdgcn_s_setprio(1);
#pragma unroll
        for (int mi = 0; mi < 8; ++mi)
#pragma unroll
            for (int ni = 0; ni < 4; ++ni)
                acc[mi][ni] = __builtin_amdgcn_mfma_f32_16x16x32_f16(
                    a[mi], b[ni], acc[mi][ni], 0, 0, 0);
        __builtin_amdgcn_s_setprio(0);

        // rotate triple buffers: cur <- nxt <- stage <- cur
        f16* tA = A0; A0 = A1; A1 = A2; A2 = tA;
        f16* tB = B0; B0 = B1; B1 = B2; B2 = tB;
    }

    // Epilogue: C/D col=lane&15 (n), row=(lane>>4)*4+j (m); fused all2all:
    // out[(n>>8)*M*256 + m*256 + (n&255)], f32 stores.
    const int R0 = row0 + wm * 128;
    const int C0 = col0 + wn * 64;
#pragma unroll
    for (int mi = 0; mi < 8; ++mi)
#pragma unroll
        for (int ni = 0; ni < 4; ++ni) {
            const int n     = C0 + ni * 16 + (lane & 15);
            const int rbase = R0 + mi * 16 + (lane >> 4) * 4;
            const size_t obase = (size_t)(n >> 8) * ((size_t)Mdim * 256) + (n & 255);
#pragma unroll
            for (int j = 0; j < 4; ++j)
                out[obase + (size_t)(rbase + j) * 256] = acc[mi][ni][j];
        }
}

// ---- Fallback (R7-verified): direct-f32 reg-staged dbuf 128^2 kernel ----
constexpr int FBM = 128, FBK = 64;
constexpr int FNWG = (Mdim / FBM) * (Ndim / FBM);
__global__ __launch_bounds__(256)
void gemm_a2a_f32_kernel(const float* __restrict__ X, const float* __restrict__ W,
                         float* __restrict__ out) {
    __shared__ f16 sA[2][FBM * FBK];
    __shared__ f16 sB[2][FBM * FBK];
    const int tid  = threadIdx.x;
    const int lane = tid & 63;
    const int wid  = tid >> 6;
    const int wr   = wid >> 1;
    const int wc   = wid & 1;
    const int cpx  = FNWG >> 3;
    const int tile = (blockIdx.x & 7) * cpx + (blockIdx.x >> 3);
    const int bn   = tile & 15;
    const int bm   = tile >> 4;
    const int row0 = bm * FBM;
    const int col0 = bn * FBM;
    f32x4 acc[4][4] = {};
    f32x4 ra[8], rb[8];
    auto load_tile = [&](int t) {
#pragma unroll
        for (int i = 0; i < 4; ++i) {
            const int c8 = i * 256 + tid;
            const int r  = c8 >> 3;
            const int cc = (c8 & 7) * 8;
            const float* pa = X + (size_t)(row0 + r) * Kdim + t * FBK + cc;
            const float* pb = W + (size_t)(col0 + r) * Kdim + t * FBK + cc;
            ra[2*i] = *(const f32x4*)pa; ra[2*i+1] = *(const f32x4*)(pa + 4);
            rb[2*i] = *(const f32x4*)pb; rb[2*i+1] = *(const f32x4*)(pb + 4);
        }
    };
    int cur = 0;
    load_tile(0);
    for (int t = 0; t < Kdim / FBK; ++t) {
#pragma unroll
        for (int i = 0; i < 4; ++i) {
            const int c8 = i * 256 + tid;
            const int sb = (c8 * 16) ^ (((c8 >> 3) & 7) << 4);
            *(f16x8*)((char*)sA[cur] + sb) = pack8(ra[2*i], ra[2*i+1]);
            *(f16x8*)((char*)sB[cur] + sb) = pack8(rb[2*i], rb[2*i+1]);
        }
        if (t + 1 < Kdim / FBK) load_tile(t + 1);
        __syncthreads();
        const f16* Ab = sA[cur];
        const f16* Bb = sB[cur];
#pragma unroll
        for (int kk = 0; kk < FBK; kk += 32) {
            const int kc = kk + (lane >> 4) * 8;
            f16x8 af[4], bfr[4];
#pragma unroll
            for (int f = 0; f < 4; ++f) {
                const int rowA = wr * 64 + f * 16 + (lane & 15);
                af[f] = *(const f16x8*)((const char*)Ab + (((rowA * FBK + kc) * 2) ^ ((rowA & 7) << 4)));
                const int rowB = wc * 64 + f * 16 + (lane & 15);
                bfr[f] = *(const f16x8*)((const char*)Bb + (((rowB * FBK + kc) * 2) ^ ((rowB & 7) << 4)));
            }
#pragma unroll
            for (int mi = 0; mi < 4; ++mi)
#pragma unroll
                for (int ni = 0; ni < 4; ++ni)
                    acc[mi][ni] = __builtin_amdgcn_mfma_f32_16x16x32_f16(
                        af[mi], bfr[ni], acc[mi][ni], 0, 0, 0);
        }
        cur ^= 1;
    }
#pragma unroll
    for (int mi = 0; mi < 4; ++mi)
#pragma unroll
        for (int ni = 0; ni < 4; ++ni) {
            const int n     = col0 + wc * 64 + ni * 16 + (lane & 15);
            const int rbase = row0 + wr * 64 + mi * 16 + (lane >> 4) * 4;
            const size_t obase = (size_t)(n >> 8) * ((size_t)Mdim * 256) + (n & 255);
#pragma unroll
            for (int j = 0; j < 4; ++j)
                out[obase + (size_t)(rbase + j) * 256] = acc[mi][ni][j];
        }
}

extern "C" void kernel_launch(void* const* d_in, const int* in_sizes, int n_in,
                              void* d_out, int out_size, void* d_ws, size_t ws_size,
                              hipStream_t stream) {
    const float* X = (const float*)d_in[0];
    const float* W = (const float*)d_in[1];
    float* out     = (float*)d_out;
    if (ws_size >= WS_NEED) {
        f16* Xs = (f16*)d_ws;
        f16* Ws = Xs + XS_ELEMS;
        hipLaunchKernelGGL(convert_kernel, dim3((int)(XS_ELEMS / 8 / 256)), dim3(256),
                           0, stream, X, Xs);
        hipLaunchKernelGGL(convert_kernel, dim3((int)(WS_ELEMS / 8 / 256)), dim3(256),
                           0, stream, W, Ws);
        hipLaunchKernelGGL(gemm_a2a_kernel, dim3(NWG), dim3(512), 0, stream, Xs, Ws, out);
    } else {
        hipLaunchKernelGGL(gemm_a2a_f32_kernel, dim3(FNWG), dim3(256), 0, stream, X, W, out);
    }
}

// Round 12
// 398.174 us; speedup vs baseline: 1.5429x; 1.0953x over previous
//
#include <hip/hip_runtime.h>

// SPModel_6846177870356: y = x@W^T + all2all permute. M=28160, N=K=2048.
// Inputs FP32 (harness-upcast fp16), output FP32.
// Round 12: 256x256, BK=64, dbuf LDS(128KB), ONE barrier per K-tile:
//   vmcnt(0) [loads issued a full tile ago -> ~0 stall] ; s_barrier ;
//   sched_barrier ; stage(t+1 -> other buf) ; reads/MFMA in 4 quadrant
//   clusters (00,01,11,10) with setprio, reads overlapping MFMA drain.
// R11 diagnosis: barrier-phased read-then-MFMA convoy + 1-blk occupancy ->
// pipes alternated. This structure lets stage-DMA + next reads overlap the
// queued MFMA drain. Pre-swizzled f16 global copies (R9-verified converts),
// conflict-free XOR ds_read, XCD-bijective swizzle, fused a2a f32 epilogue.

typedef _Float16 f16;
typedef _Float16 f16x2 __attribute__((ext_vector_type(2)));
typedef _Float16 f16x8 __attribute__((ext_vector_type(8)));
typedef float    f32x4 __attribute__((ext_vector_type(4)));

#define GPTR(p) ((const __attribute__((address_space(1))) void*)(p))
#define LPTR(p) ((__attribute__((address_space(3))) void*)(p))

constexpr int Mdim = 28160;   // 8*44*80
constexpr int Ndim = 2048;
constexpr int Kdim = 2048;
constexpr int BM = 256, BN = 256, BK = 64;
constexpr int NWG = (Mdim / BM) * (Ndim / BN);  // 110*8 = 880 (%8==0)
constexpr int NT  = Kdim / BK;                  // 32
constexpr size_t XS_ELEMS = (size_t)Mdim * Kdim;
constexpr size_t WS_ELEMS = (size_t)Ndim * Kdim;
constexpr size_t WS_NEED  = (XS_ELEMS + WS_ELEMS) * sizeof(f16);

__device__ __forceinline__ f16x8 pack8(const f32x4& lo, const f32x4& hi) {
    f16x2 p0 = __builtin_bit_cast(f16x2, __builtin_amdgcn_cvt_pkrtz(lo[0], lo[1]));
    f16x2 p1 = __builtin_bit_cast(f16x2, __builtin_amdgcn_cvt_pkrtz(lo[2], lo[3]));
    f16x2 p2 = __builtin_bit_cast(f16x2, __builtin_amdgcn_cvt_pkrtz(hi[0], hi[1]));
    f16x2 p3 = __builtin_bit_cast(f16x2, __builtin_amdgcn_cvt_pkrtz(hi[2], hi[3]));
    return (f16x8){p0[0], p0[1], p1[0], p1[1], p2[0], p2[1], p3[0], p3[1]};
}

// f32 [rows x 2048] -> f16 pre-swizzled: dst[m][(k8 ^ (m&7))*8] (R9-verified).
__global__ __launch_bounds__(256)
void convert_kernel(const float* __restrict__ src, f16* __restrict__ dst) {
    const int idx = blockIdx.x * 256 + threadIdx.x;
    const int m   = idx >> 8;
    const int k8  = idx & 255;
    const int k8s = k8 ^ (m & 7);
    const float* p = src + (size_t)m * Kdim + k8 * 8;
    f32x4 lo = *(const f32x4*)p;
    f32x4 hi = *(const f32x4*)(p + 4);
    *(f16x8*)(dst + (size_t)m * Kdim + k8s * 8) = pack8(lo, hi);
}

// swizzled LDS read: row stride 128B, byte ^= (row&7)<<4 (R9: 0 conflicts)
__device__ __forceinline__ f16x8 lds_frag(const f16* base, int r, int kc) {
    const int b = ((r * BK + kc) * 2) ^ ((r & 7) << 4);
    return *(const f16x8*)((const char*)base + b);
}

__global__ __launch_bounds__(512, 2)
void gemm_a2a_kernel(const f16* __restrict__ Xs, const f16* __restrict__ Ws,
                     float* __restrict__ out) {
    __shared__ f16 sA[2][BM * BK];   // 32 KiB each (swizzled image)
    __shared__ f16 sB[2][BN * BK];   // total 128 KiB

    const int tid  = threadIdx.x;
    const int lane = tid & 63;
    const int wid  = tid >> 6;
    const int wm   = wid >> 2;          // 0..1 -> 128 M-rows
    const int wn   = wid & 3;           // 0..3 -> 64 N-cols

    const int cpx  = NWG >> 3;                       // XCD-bijective swizzle
    const int tile = (blockIdx.x & 7) * cpx + (blockIdx.x >> 3);
    const int bn   = tile & 7;
    const int bm   = tile >> 3;
    const int row0 = bm * BM;
    const int col0 = bn * BN;

    f32x4 acc[8][4] = {};

    // Stage K-tile t into buf d: 2048 16B chunks each for A and B, linear LDS
    // dest; global source pre-swizzled so linear image = swizzled layout.
    auto stage = [&](int t, int d) {
#pragma unroll
        for (int h = 0; h < 4; ++h) {
            const int c  = h * 512 + tid;
            const int r  = c >> 3;
            const int cc = (c & 7) * 8;
            __builtin_amdgcn_global_load_lds(
                GPTR(Xs + (size_t)(row0 + r) * Kdim + t * BK + cc),
                LPTR(&sA[d][c * 8]), 16, 0, 0);
            __builtin_amdgcn_global_load_lds(
                GPTR(Ws + (size_t)(col0 + r) * Kdim + t * BK + cc),
                LPTR(&sB[d][c * 8]), 16, 0, 0);
        }
    };

    stage(0, 0);   // 8 loads in flight

    const int lr = lane & 15;           // frag row within 16
    const int kq = (lane >> 4) * 8;     // frag k-offset

    for (int t = 0; t < NT; ++t) {
        const int d = t & 1;
        // tile t's loads were issued a full tile ago -> near-zero wait.
        asm volatile("s_waitcnt vmcnt(0)" ::: "memory");
        __builtin_amdgcn_s_barrier();        // tile t certified in LDS, all waves
        __builtin_amdgcn_sched_barrier(0);   // pin: nothing hoists above
        if (t + 1 < NT) stage(t + 1, d ^ 1); // WAR-safe: d^1 readers pre-barrier

        const f16* Ab = sA[d];
        const f16* Bb = sB[d];

        f16x8 b0[2][2], b1[2][2], a[4][2];
#pragma unroll
        for (int gg = 0; gg < 2; ++gg)
#pragma unroll
            for (int kk = 0; kk < 2; ++kk) {
                b0[gg][kk] = lds_frag(Bb, wn * 64 +      gg * 16 + lr, kk * 32 + kq);
                b1[gg][kk] = lds_frag(Bb, wn * 64 + 32 + gg * 16 + lr, kk * 32 + kq);
            }
#pragma unroll
        for (int f = 0; f < 4; ++f)
#pragma unroll
            for (int kk = 0; kk < 2; ++kk)
                a[f][kk] = lds_frag(Ab, wm * 128 + f * 16 + lr, kk * 32 + kq);

        // quadrant (m0,n0) and (m0,n1): a reused, then dies
        __builtin_amdgcn_s_setprio(1);
#pragma unroll
        for (int f = 0; f < 4; ++f)
#pragma unroll
            for (int gg = 0; gg < 2; ++gg)
#pragma unroll
                for (int kk = 0; kk < 2; ++kk)
                    acc[f][gg] = __builtin_amdgcn_mfma_f32_16x16x32_f16(
                        a[f][kk], b0[gg][kk], acc[f][gg], 0, 0, 0);
#pragma unroll
        for (int f = 0; f < 4; ++f)
#pragma unroll
            for (int gg = 0; gg < 2; ++gg)
#pragma unroll
                for (int kk = 0; kk < 2; ++kk)
                    acc[f][2 + gg] = __builtin_amdgcn_mfma_f32_16x16x32_f16(
                        a[f][kk], b1[gg][kk], acc[f][2 + gg], 0, 0, 0);
        __builtin_amdgcn_s_setprio(0);

        // reload a for m-half 1; overlaps previous clusters' pipe drain
#pragma unroll
        for (int f = 0; f < 4; ++f)
#pragma unroll
            for (int kk = 0; kk < 2; ++kk)
                a[f][kk] = lds_frag(Ab, wm * 128 + 64 + f * 16 + lr, kk * 32 + kq);

        __builtin_amdgcn_s_setprio(1);
#pragma unroll
        for (int f = 0; f < 4; ++f)
#pragma unroll
            for (int gg = 0; gg < 2; ++gg)
#pragma unroll
                for (int kk = 0; kk < 2; ++kk)
                    acc[4 + f][2 + gg] = __builtin_amdgcn_mfma_f32_16x16x32_f16(
                        a[f][kk], b1[gg][kk], acc[4 + f][2 + gg], 0, 0, 0);
#pragma unroll
        for (int f = 0; f < 4; ++f)
#pragma unroll
            for (int gg = 0; gg < 2; ++gg)
#pragma unroll
                for (int kk = 0; kk < 2; ++kk)
                    acc[4 + f][gg] = __builtin_amdgcn_mfma_f32_16x16x32_f16(
                        a[f][kk], b0[gg][kk], acc[4 + f][gg], 0, 0, 0);
        __builtin_amdgcn_s_setprio(0);
    }

    // Epilogue: C/D col=lane&15 (n), row=(lane>>4)*4+j (m); fused all2all:
    // out[(n>>8)*M*256 + m*256 + (n&255)], f32 stores.
    const int R0 = row0 + wm * 128;
    const int C0 = col0 + wn * 64;
#pragma unroll
    for (int mi = 0; mi < 8; ++mi)
#pragma unroll
        for (int ni = 0; ni < 4; ++ni) {
            const int n     = C0 + ni * 16 + (lane & 15);
            const int rbase = R0 + mi * 16 + (lane >> 4) * 4;
            const size_t obase = (size_t)(n >> 8) * ((size_t)Mdim * 256) + (n & 255);
#pragma unroll
            for (int j = 0; j < 4; ++j)
                out[obase + (size_t)(rbase + j) * 256] = acc[mi][ni][j];
        }
}

// ---- Fallback (R7-verified): direct-f32 reg-staged dbuf 128^2 kernel ----
constexpr int FBM = 128, FBK = 64;
constexpr int FNWG = (Mdim / FBM) * (Ndim / FBM);
__global__ __launch_bounds__(256)
void gemm_a2a_f32_kernel(const float* __restrict__ X, const float* __restrict__ W,
                         float* __restrict__ out) {
    __shared__ f16 sA[2][FBM * FBK];
    __shared__ f16 sB[2][FBM * FBK];
    const int tid  = threadIdx.x;
    const int lane = tid & 63;
    const int wid  = tid >> 6;
    const int wr   = wid >> 1;
    const int wc   = wid & 1;
    const int cpx  = FNWG >> 3;
    const int tile = (blockIdx.x & 7) * cpx + (blockIdx.x >> 3);
    const int bn   = tile & 15;
    const int bm   = tile >> 4;
    const int row0 = bm * FBM;
    const int col0 = bn * FBM;
    f32x4 acc[4][4] = {};
    f32x4 ra[8], rb[8];
    auto load_tile = [&](int t) {
#pragma unroll
        for (int i = 0; i < 4; ++i) {
            const int c8 = i * 256 + tid;
            const int r  = c8 >> 3;
            const int cc = (c8 & 7) * 8;
            const float* pa = X + (size_t)(row0 + r) * Kdim + t * FBK + cc;
            const float* pb = W + (size_t)(col0 + r) * Kdim + t * FBK + cc;
            ra[2*i] = *(const f32x4*)pa; ra[2*i+1] = *(const f32x4*)(pa + 4);
            rb[2*i] = *(const f32x4*)pb; rb[2*i+1] = *(const f32x4*)(pb + 4);
        }
    };
    int cur = 0;
    load_tile(0);
    for (int t = 0; t < Kdim / FBK; ++t) {
#pragma unroll
        for (int i = 0; i < 4; ++i) {
            const int c8 = i * 256 + tid;
            const int sb = (c8 * 16) ^ (((c8 >> 3) & 7) << 4);
            *(f16x8*)((char*)sA[cur] + sb) = pack8(ra[2*i], ra[2*i+1]);
            *(f16x8*)((char*)sB[cur] + sb) = pack8(rb[2*i], rb[2*i+1]);
        }
        if (t + 1 < Kdim / FBK) load_tile(t + 1);
        __syncthreads();
        const f16* Ab = sA[cur];
        const f16* Bb = sB[cur];
#pragma unroll
        for (int kk = 0; kk < FBK; kk += 32) {
            const int kc = kk + (lane >> 4) * 8;
            f16x8 af[4], bfr[4];
#pragma unroll
            for (int f = 0; f < 4; ++f) {
                const int rowA = wr * 64 + f * 16 + (lane & 15);
                af[f] = *(const f16x8*)((const char*)Ab + (((rowA * FBK + kc) * 2) ^ ((rowA & 7) << 4)));
                const int rowB = wc * 64 + f * 16 + (lane & 15);
                bfr[f] = *(const f16x8*)((const char*)Bb + (((rowB * FBK + kc) * 2) ^ ((rowB & 7) << 4)));
            }
#pragma unroll
            for (int mi = 0; mi < 4; ++mi)
#pragma unroll
                for (int ni = 0; ni < 4; ++ni)
                    acc[mi][ni] = __builtin_amdgcn_mfma_f32_16x16x32_f16(
                        af[mi], bfr[ni], acc[mi][ni], 0, 0, 0);
        }
        cur ^= 1;
    }
#pragma unroll
    for (int mi = 0; mi < 4; ++mi)
#pragma unroll
        for (int ni = 0; ni < 4; ++ni) {
            const int n     = col0 + wc * 64 + ni * 16 + (lane & 15);
            const int rbase = row0 + wr * 64 + mi * 16 + (lane >> 4) * 4;
            const size_t obase = (size_t)(n >> 8) * ((size_t)Mdim * 256) + (n & 255);
#pragma unroll
            for (int j = 0; j < 4; ++j)
                out[obase + (size_t)(rbase + j) * 256] = acc[mi][ni][j];
        }
}

extern "C" void kernel_launch(void* const* d_in, const int* in_sizes, int n_in,
                              void* d_out, int out_size, void* d_ws, size_t ws_size,
                              hipStream_t stream) {
    const float* X = (const float*)d_in[0];
    const float* W = (const float*)d_in[1];
    float* out     = (float*)d_out;
    if (ws_size >= WS_NEED) {
        f16* Xs = (f16*)d_ws;
        f16* Ws = Xs + XS_ELEMS;
        hipLaunchKernelGGL(convert_kernel, dim3((int)(XS_ELEMS / 8 / 256)), dim3(256),
                           0, stream, X, Xs);
        hipLaunchKernelGGL(convert_kernel, dim3((int)(WS_ELEMS / 8 / 256)), dim3(256),
                           0, stream, W, Ws);
        hipLaunchKernelGGL(gemm_a2a_kernel, dim3(NWG), dim3(512), 0, stream, Xs, Ws, out);
    } else {
        hipLaunchKernelGGL(gemm_a2a_f32_kernel, dim3(FNWG), dim3(256), 0, stream, X, W, out);
    }
}